// Round 11
// baseline (88.064 us; speedup 1.0000x reference)
//
#include <hip/hip_runtime.h>
#include <hip/hip_bf16.h>
#include <math.h>

#define N_ 256
#define C_ 100
#define D_ 512
#define ST 368          // Gram stride (23 tiles of 16)
#define NTILE 23
#define NWTILE 529      // 23*23 wave-tiles
#define NPRBLK 257      // 256 pair blocks (8 waves, split-LSE) + 1 real block
#define LOG2E 1.44269504088896f

typedef __attribute__((ext_vector_type(8))) short short8;
typedef __attribute__((ext_vector_type(4))) float floatx4;

__device__ inline float waveReduceSum(float v) {
    #pragma unroll
    for (int off = 32; off > 0; off >>= 1) v += __shfl_xor(v, off, 64);
    return v;
}
__device__ inline float clip1(float x) { return fminf(fmaxf(x, -1.0f), 1.0f); }

__device__ inline short8 cvt8(float4 a, float4 b) {
    union { __hip_bfloat16 h[8]; short8 s; } u;
    u.h[0] = __float2bfloat16(a.x); u.h[1] = __float2bfloat16(a.y);
    u.h[2] = __float2bfloat16(a.z); u.h[3] = __float2bfloat16(a.w);
    u.h[4] = __float2bfloat16(b.x); u.h[5] = __float2bfloat16(b.y);
    u.h[6] = __float2bfloat16(b.z); u.h[7] = __float2bfloat16(b.w);
    return u.s;
}

// Partial softmax-denominator over classes [C0,C1): sum exp2(sp[c]*(la*r1[c]+lb*r2[c])).
template <int C0, int C1>
__device__ inline float lseAccum(const float* __restrict__ row1,
                                 const float* __restrict__ row2,
                                 const float* __restrict__ sp,
                                 float la, float lb) {
    float sm0 = 0.0f, sm1 = 0.0f, sm2 = 0.0f, sm3 = 0.0f;
    #pragma unroll
    for (int c = C0; c < C1; c += 4) {
        float4 a1 = *(const float4*)(row1 + c);
        float4 a2 = *(const float4*)(row2 + c);
        float4 s4 = *(const float4*)(sp + c);
        sm0 += exp2f(s4.x * (la * a1.x + lb * a2.x));
        sm1 += exp2f(s4.y * (la * a1.y + lb * a2.y));
        sm2 += exp2f(s4.z * (la * a1.z + lb * a2.z));
        sm3 += exp2f(s4.w * (la * a1.w + lb * a2.w));
    }
    return (sm0 + sm1) + (sm2 + sm3);
}

// K1: Gram = Y Y^T with Y = [X;P] cast to bf16 in-register (validated R6-R10,
// absmax 0.0). One 16x16 tile/wave via mfma_f32_16x16x32_bf16.
// C/D: col=lane&15, row=quad*4+reg (m89). Rows >= 356 clamp to 0 (garbage,
// finite, never consumed). Diag tiles emit rn[r] = 3*rsqrt(G[r][r]).
__global__ void gemm_kernel(const float* __restrict__ X,
                            const float* __restrict__ P,
                            float* __restrict__ G,
                            float* __restrict__ rn) {
    int wid = blockIdx.x * 4 + (threadIdx.x >> 6);
    if (wid >= NWTILE) return;
    int lane = threadIdx.x & 63;
    int r = lane & 15, quad = lane >> 4;
    int tm = wid / NTILE, tn = wid - tm * NTILE;
    int ra = tm * 16 + r; if (ra >= 356) ra = 0;
    int rb = tn * 16 + r; if (rb >= 356) rb = 0;
    const float* arow = (ra < N_) ? (X + (size_t)ra * D_) : (P + (size_t)(ra - N_) * D_);
    const float* brow = (rb < N_) ? (X + (size_t)rb * D_) : (P + (size_t)(rb - N_) * D_);
    floatx4 acc = {0.0f, 0.0f, 0.0f, 0.0f};
    #pragma unroll
    for (int kc = 0; kc < D_; kc += 32) {
        const float4* ap = (const float4*)(arow + kc + quad * 8);
        const float4* bp = (const float4*)(brow + kc + quad * 8);
        short8 av = cvt8(ap[0], ap[1]);
        short8 bv = cvt8(bp[0], bp[1]);
        acc = __builtin_amdgcn_mfma_f32_16x16x32_bf16(av, bv, acc, 0, 0, 0);
    }
    int row0 = tm * 16 + quad * 4, col = tn * 16 + r;
    #pragma unroll
    for (int i = 0; i < 4; ++i)
        G[(size_t)(row0 + i) * ST + col] = acc[i];
    if (tm == tn && (r >> 2) == quad) {
        float d = acc[r & 3];                        // Gram[col][col]
        rn[tm * 16 + r] = 3.0f * rsqrtf(fmaxf(d, 1e-24f));
    }
}

// K2: pair + real losses + self-contained finalize. 512 threads = 8 waves.
//  Pair blocks [0,256): block b owns jobs 4b..4b+3; job j = 64 pairs
//    (i1 = j>>2 wave-uniform, i2 = (j&3)*64+lane). TWO waves per job
//    (half = w&1) split the 100-class LSE sum [0,52)/[52,100); half-1
//    writes its per-lane partial to LDS, half-0 combines + logf.
//    -> 2 waves/SIMD of TLP (was 1), halving exposed exp/load latency.
//  Block 256: waves 0..3 do the 256 real rows (full 100-class loop).
//  Every block computes count redundantly (LDS histogram) and adds
//  block_partial/count to out[0] with one plain atomicAdd (no fences).
__global__ __launch_bounds__(512)
void pair_real_kernel(const float* __restrict__ G,
                      const float* __restrict__ rn,
                      const int* __restrict__ T,
                      float* __restrict__ out) {
    __shared__ int hist[C_];
    __shared__ float scnt[8], part[4][64], ssum[4];
    int t = threadIdx.x;
    int w = t >> 6, lane = t & 63;

    // --- per-block count (redundant, no inter-block traffic) ---
    if (t < C_) hist[t] = 0;
    __syncthreads();
    if (t < N_) atomicAdd(&hist[T[t]], 1);
    __syncthreads();
    float same = 0.0f;
    if (t < C_) { float n = (float)hist[t]; same = 0.5f * n * (n - 1.0f); }
    same = waveReduceSum(same);
    if (lane == 0) scnt[w] = same;
    __syncthreads();
    float cnt = 256.0f + 32640.0f
              - (((scnt[0] + scnt[1]) + (scnt[2] + scnt[3]))
               + ((scnt[4] + scnt[5]) + (scnt[6] + scnt[7])));

    const float* sp = rn + 256;                      // proxy scales
    int blk = blockIdx.x;

    if (blk < 256) {
        int j    = blk * 4 + (w >> 1);               // job [0,1024)
        int half = w & 1;
        int i1 = j >> 2;                             // wave-uniform
        int i2 = ((j & 3) << 6) + lane;              // lane-consecutive
        int t1 = T[i1], t2 = T[i2];
        bool active = (i2 > i1) && (t2 != t1);
        float s1 = rn[i1], sc2 = rn[i2];
        const float* row1 = G + (size_t)i1 * ST + 256;
        const float* row2 = G + (size_t)i2 * ST + 256;
        float ip1t1 = row1[t1] * s1 * sp[t1];
        float ip1t2 = row1[t2] * s1 * sp[t2];
        float ip2t1 = row2[t1] * sc2 * sp[t1];
        float ip2t2 = row2[t2] * sc2 * sp[t2];
        float X1P1 = clip1(ip1t1), X1P2 = clip1(ip1t2);
        float X2P1 = clip1(ip2t1), X2P2 = clip1(ip2t2);
        float num = X2P2 - X2P1;
        float den = num + X1P1 - X1P2;
        float lam = fminf(fmaxf(num / den, 0.3f), 0.7f);
        float oml = 1.0f - lam;
        float g = G[(size_t)i1 * ST + i2] * s1 * sc2;
        float wn2 = 9.0f * (lam * lam + oml * oml) + 2.0f * lam * oml * g;
        float ss2 = 6.0f * rsqrtf(fmaxf(wn2, 1e-24f));
        float la = ss2 * lam * s1 * LOG2E, lb = ss2 * oml * sc2 * LOG2E;

        float sm = half ? lseAccum<52, 100>(row1, row2, sp, la, lb)
                        : lseAccum<0, 52>(row1, row2, sp, la, lb);
        if (half) part[w >> 1][lane] = sm;
        __syncthreads();
        float contrib = 0.0f;
        if (!half) {
            float LSE = logf(sm + part[w >> 1][lane]);
            float ec1 = ss2 * (lam * ip1t1 + oml * ip2t1);
            float ec2 = ss2 * (lam * ip1t2 + oml * ip2t2);
            contrib = active ? (LSE - lam * ec1 - oml * ec2) : 0.0f;
        }
        contrib = waveReduceSum(contrib);
        if (lane == 0 && !half) ssum[w >> 1] = contrib;
        __syncthreads();
        if (t == 0)
            atomicAdd(out, (ssum[0] + ssum[1] + ssum[2] + ssum[3]) / cnt);
    } else {
        // real rows: waves 0..3 cover i = w*64+lane; waves 4..7 contribute 0
        float contrib = 0.0f;
        if (w < 4) {
            int i = w * 64 + lane;                   // [0, 256)
            float si2 = 2.0f * rn[i];
            const float* row = G + (size_t)i * ST + 256;
            float sum = lseAccum<0, 100>(row, row, sp, si2 * LOG2E, 0.0f);
            float LSE = logf(sum);
            int tt = T[i];
            contrib = LSE - si2 * row[tt] * sp[tt];
        }
        contrib = waveReduceSum(contrib);
        if (lane == 0 && w < 4) ssum[w] = contrib;
        __syncthreads();
        if (t == 0)
            atomicAdd(out, (ssum[0] + ssum[1] + ssum[2] + ssum[3]) / cnt);
    }
}

extern "C" void kernel_launch(void* const* d_in, const int* in_sizes, int n_in,
                              void* d_out, int out_size, void* d_ws, size_t ws_size,
                              hipStream_t stream) {
    const float* X = (const float*)d_in[0];   // (256, 512) f32
    const float* P = (const float*)d_in[1];   // (100, 512) f32
    const int*   T = (const int*)d_in[2];     // (256,) i32
    // d_in[3] = indices, unused
    float* ws = (float*)d_ws;
    float* G  = ws;                           // 368*368 = 135424
    float* rn = ws + 135424;                  // 368    (total ~531 KB)
    float* out = (float*)d_out;

    gemm_kernel<<<133, 256, 0, stream>>>(X, P, G, rn);
    pair_real_kernel<<<NPRBLK, 512, 0, stream>>>(G, rn, T, out);
}

// Round 12
// 75.619 us; speedup vs baseline: 1.1646x; 1.1646x over previous
//
#include <hip/hip_runtime.h>
#include <hip/hip_bf16.h>
#include <math.h>

#define N_ 256
#define C_ 100
#define D_ 512
#define ST 368          // Gram stride (23 tiles of 16)
#define NTILE 23
#define NWTILE 529      // 23*23 wave-tiles
#define NPRBLK 257      // 1028 waves: 1024 pair-waves (64 pairs each) + 4 real-waves
#define LOG2E 1.44269504088896f

typedef __attribute__((ext_vector_type(8))) short short8;
typedef __attribute__((ext_vector_type(4))) float floatx4;

__device__ inline float waveReduceSum(float v) {
    #pragma unroll
    for (int off = 32; off > 0; off >>= 1) v += __shfl_xor(v, off, 64);
    return v;
}
__device__ inline float clip1(float x) { return fminf(fmaxf(x, -1.0f), 1.0f); }

__device__ inline short8 cvt8(float4 a, float4 b) {
    union { __hip_bfloat16 h[8]; short8 s; } u;
    u.h[0] = __float2bfloat16(a.x); u.h[1] = __float2bfloat16(a.y);
    u.h[2] = __float2bfloat16(a.z); u.h[3] = __float2bfloat16(a.w);
    u.h[4] = __float2bfloat16(b.x); u.h[5] = __float2bfloat16(b.y);
    u.h[6] = __float2bfloat16(b.z); u.h[7] = __float2bfloat16(b.w);
    return u.s;
}

// K1: Gram = Y Y^T with Y = [X;P] cast to bf16 in-register (validated R6-R10,
// absmax 0.0). One 16x16 tile/wave via mfma_f32_16x16x32_bf16.
// C/D: col=lane&15, row=quad*4+reg (m89). Rows >= 356 clamp to 0 (garbage,
// finite, never consumed). Diag tiles emit rn[r] = 3*rsqrt(G[r][r]).
__global__ void gemm_kernel(const float* __restrict__ X,
                            const float* __restrict__ P,
                            float* __restrict__ G,
                            float* __restrict__ rn) {
    int wid = blockIdx.x * 4 + (threadIdx.x >> 6);
    if (wid >= NWTILE) return;
    int lane = threadIdx.x & 63;
    int r = lane & 15, quad = lane >> 4;
    int tm = wid / NTILE, tn = wid - tm * NTILE;
    int ra = tm * 16 + r; if (ra >= 356) ra = 0;
    int rb = tn * 16 + r; if (rb >= 356) rb = 0;
    const float* arow = (ra < N_) ? (X + (size_t)ra * D_) : (P + (size_t)(ra - N_) * D_);
    const float* brow = (rb < N_) ? (X + (size_t)rb * D_) : (P + (size_t)(rb - N_) * D_);
    floatx4 acc = {0.0f, 0.0f, 0.0f, 0.0f};
    #pragma unroll
    for (int kc = 0; kc < D_; kc += 32) {
        const float4* ap = (const float4*)(arow + kc + quad * 8);
        const float4* bp = (const float4*)(brow + kc + quad * 8);
        short8 av = cvt8(ap[0], ap[1]);
        short8 bv = cvt8(bp[0], bp[1]);
        acc = __builtin_amdgcn_mfma_f32_16x16x32_bf16(av, bv, acc, 0, 0, 0);
    }
    int row0 = tm * 16 + quad * 4, col = tn * 16 + r;
    #pragma unroll
    for (int i = 0; i < 4; ++i)
        G[(size_t)(row0 + i) * ST + col] = acc[i];
    if (tm == tn && (r >> 2) == quad) {
        float d = acc[r & 3];                        // Gram[col][col]
        rn[tm * 16 + r] = 3.0f * rsqrtf(fmaxf(d, 1e-24f));
    }
}

// K2: pair + real losses + SELF-CONTAINED finalize (R10 config, best known):
//  - each block redundantly computes count = 256 + 32640 - sum_c n_c(n_c-1)/2
//    from T via a 100-bin LDS histogram (parallel, no inter-block traffic);
//  - one lane per pair: i1 = pid>>8 wave-uniform, i2 = pid&255
//    lane-consecutive; serial 100-class LSE per lane via native exp2f
//    (log2e folded into logit constants);
//  - block partial / count added to out[0] with ONE plain atomicAdd per block
//    (257 adds, commutative, no fences).
__global__ void pair_real_kernel(const float* __restrict__ G,
                                 const float* __restrict__ rn,
                                 const int* __restrict__ T,
                                 float* __restrict__ out) {
    __shared__ int hist[C_];
    __shared__ float s2[4], ssum[4];
    int t = threadIdx.x;
    int w = t >> 6, lane = t & 63;

    // --- per-block count (redundant, cheap) ---
    if (t < C_) hist[t] = 0;
    __syncthreads();
    atomicAdd(&hist[T[t]], 1);
    __syncthreads();
    float same = 0.0f;
    if (t < C_) { float n = (float)hist[t]; same = 0.5f * n * (n - 1.0f); }
    float rs = waveReduceSum(same);
    if (lane == 0) s2[w] = rs;
    __syncthreads();
    float cnt = 256.0f + 32640.0f - (s2[0] + s2[1] + s2[2] + s2[3]);

    // --- pair / real work ---
    int gw = blockIdx.x * 4 + w;
    const float* sp = rn + 256;                      // proxy scales
    float contrib = 0.0f;
    if (gw < 1024) {
        int pid = gw * 64 + lane;
        int i1 = pid >> 8;                           // wave-uniform
        int i2 = pid & 255;                          // lane-consecutive
        int t1 = T[i1], t2 = T[i2];
        bool active = (i2 > i1) && (t2 != t1);
        float s1 = rn[i1], sc2 = rn[i2];
        const float* row1 = G + (size_t)i1 * ST + 256;
        const float* row2 = G + (size_t)i2 * ST + 256;
        float ip1t1 = row1[t1] * s1 * sp[t1];
        float ip1t2 = row1[t2] * s1 * sp[t2];
        float ip2t1 = row2[t1] * sc2 * sp[t1];
        float ip2t2 = row2[t2] * sc2 * sp[t2];
        float X1P1 = clip1(ip1t1), X1P2 = clip1(ip1t2);
        float X2P1 = clip1(ip2t1), X2P2 = clip1(ip2t2);
        float num = X2P2 - X2P1;
        float den = num + X1P1 - X1P2;
        float lam = fminf(fmaxf(num / den, 0.3f), 0.7f);
        float oml = 1.0f - lam;
        float g = G[(size_t)i1 * ST + i2] * s1 * sc2;
        float wn2 = 9.0f * (lam * lam + oml * oml) + 2.0f * lam * oml * g;
        float ss2 = 6.0f * rsqrtf(fmaxf(wn2, 1e-24f));
        float la = ss2 * lam * s1 * LOG2E, lb = ss2 * oml * sc2 * LOG2E;
        float sm0 = 0.0f, sm1 = 0.0f, sm2 = 0.0f, sm3 = 0.0f;
        #pragma unroll 5
        for (int c = 0; c < C_; c += 4) {
            float4 a1 = *(const float4*)(row1 + c);  // uniform -> broadcast
            float4 a2 = *(const float4*)(row2 + c);  // per-lane gather
            float4 s4 = *(const float4*)(sp + c);    // uniform
            sm0 += exp2f(s4.x * (la * a1.x + lb * a2.x));
            sm1 += exp2f(s4.y * (la * a1.y + lb * a2.y));
            sm2 += exp2f(s4.z * (la * a1.z + lb * a2.z));
            sm3 += exp2f(s4.w * (la * a1.w + lb * a2.w));
        }
        float LSE = logf((sm0 + sm1) + (sm2 + sm3));
        float ec1 = ss2 * (lam * ip1t1 + oml * ip2t1);
        float ec2 = ss2 * (lam * ip1t2 + oml * ip2t2);
        contrib = active ? (LSE - lam * ec1 - oml * ec2) : 0.0f;
    } else {
        int i = (gw - 1024) * 64 + lane;             // [0, 256)
        float si2 = 2.0f * rn[i];
        float si2L = si2 * LOG2E;
        const float* row = G + (size_t)i * ST + 256;
        float sm0 = 0.0f, sm1 = 0.0f, sm2 = 0.0f, sm3 = 0.0f;
        #pragma unroll 5
        for (int c = 0; c < C_; c += 4) {
            float4 a = *(const float4*)(row + c);
            float4 s4 = *(const float4*)(sp + c);
            sm0 += exp2f(si2L * a.x * s4.x);
            sm1 += exp2f(si2L * a.y * s4.y);
            sm2 += exp2f(si2L * a.z * s4.z);
            sm3 += exp2f(si2L * a.w * s4.w);
        }
        float LSE = logf((sm0 + sm1) + (sm2 + sm3));
        int tt = T[i];
        contrib = LSE - si2 * row[tt] * sp[tt];
    }
    contrib = waveReduceSum(contrib);
    if (lane == 0) ssum[w] = contrib;
    __syncthreads();
    if (t == 0) {
        float bs = ssum[0] + ssum[1] + ssum[2] + ssum[3];
        atomicAdd(out, bs / cnt);
    }
}

extern "C" void kernel_launch(void* const* d_in, const int* in_sizes, int n_in,
                              void* d_out, int out_size, void* d_ws, size_t ws_size,
                              hipStream_t stream) {
    const float* X = (const float*)d_in[0];   // (256, 512) f32
    const float* P = (const float*)d_in[1];   // (100, 512) f32
    const int*   T = (const int*)d_in[2];     // (256,) i32
    // d_in[3] = indices, unused
    float* ws = (float*)d_ws;
    float* G  = ws;                           // 368*368 = 135424
    float* rn = ws + 135424;                  // 368    (total ~531 KB)
    float* out = (float*)d_out;

    gemm_kernel<<<133, 256, 0, stream>>>(X, P, G, rn);
    pair_real_kernel<<<NPRBLK, 256, 0, stream>>>(G, rn, T, out);
}